// Round 1
// baseline (1537.976 us; speedup 1.0000x reference)
//
#include <hip/hip_runtime.h>
#include <math.h>

// ---------------------------------------------------------------------------
// GOTSim: GCN feats (dense per-graph adjacency) -> GED cost matrices ->
// batched 64x64 Jonker-Volgenant LAP -> sigmoid head.
// B=256 pairs, S=32 nodes, L=3 layers, FIN=512, F=256.
// ---------------------------------------------------------------------------

#define LAP_INF 1e30f

// ---- build adjacency counts (multi-edges counted, like segment_sum) -------
__global__ __launch_bounds__(256) void count_edges_k(const int* __restrict__ eiq,
                                                     const int* __restrict__ eic,
                                                     float* __restrict__ adj, int ne) {
  int e = blockIdx.x * 256 + threadIdx.x;
  if (e >= ne) return;
  const int side = blockIdx.y;
  const int* ei = side ? eic : eiq;
  int s = ei[e];
  int d = ei[ne + e];
  int g = d >> 5;  // S=32; edges never cross graphs by construction
  atomicAdd(&adj[((side << 8) + g) * 1024 + (d & 31) * 32 + (s & 31)], 1.0f);
}

// ---- add self loops, deg^-1/2 sym-normalize (in place) --------------------
__global__ __launch_bounds__(256) void norm_adj_k(float* __restrict__ adj) {
  __shared__ float s[1024];
  __shared__ float dinv[32];
  float* A = adj + (size_t)blockIdx.x * 1024;
  const int t = threadIdx.x;
  for (int k = t; k < 1024; k += 256) s[k] = A[k];
  __syncthreads();
  if (t < 32) s[t * 32 + t] += 1.0f;  // self loop
  __syncthreads();
  if (t < 32) {
    float d = 0.f;
#pragma unroll
    for (int j = 0; j < 32; ++j) d += s[t * 32 + j];
    dinv[t] = rsqrtf(d);  // deg = in-degree incl. self loop
  }
  __syncthreads();
  for (int k = t; k < 1024; k += 256)
    A[k] = s[k] * dinv[k >> 5] * dinv[k & 31];
}

// ---- Y = act(X) @ W  (M=8192, N=256), 64x64 tile, 4x4 per thread ----------
template <bool RELU>
__global__ __launch_bounds__(256) void gemm_k(const float* __restrict__ Xq,
                                              const float* __restrict__ Xc,
                                              const float* __restrict__ W,
                                              float* __restrict__ Yq,
                                              float* __restrict__ Yc, int K) {
  const float* X = blockIdx.z ? Xc : Xq;
  float* Y = blockIdx.z ? Yc : Yq;
  const int m0 = blockIdx.x * 64, n0 = blockIdx.y * 64;
  __shared__ float As[16][64];
  __shared__ float Bs[16][64];
  const int t = threadIdx.x;
  const int tx = t & 15, ty = t >> 4;
  const int lam = t >> 2, lak = (t & 3) << 2;  // A-tile load: row, k-quad
  const int lbk = t >> 4, lbn = (t & 15) << 2; // B-tile load
  float acc[4][4] = {};
  for (int k0 = 0; k0 < K; k0 += 16) {
    float4 av = *(const float4*)(X + (size_t)(m0 + lam) * K + k0 + lak);
    float4 bv = *(const float4*)(W + (size_t)(k0 + lbk) * 256 + n0 + lbn);
    if (RELU) {
      av.x = fmaxf(av.x, 0.f); av.y = fmaxf(av.y, 0.f);
      av.z = fmaxf(av.z, 0.f); av.w = fmaxf(av.w, 0.f);
    }
    As[lak + 0][lam] = av.x;
    As[lak + 1][lam] = av.y;
    As[lak + 2][lam] = av.z;
    As[lak + 3][lam] = av.w;
    *(float4*)&Bs[lbk][lbn] = bv;
    __syncthreads();
#pragma unroll
    for (int kk = 0; kk < 16; ++kk) {
      float a[4], b[4];
      *(float4*)a = *(const float4*)&As[kk][ty << 2];
      *(float4*)b = *(const float4*)&Bs[kk][tx << 2];
#pragma unroll
      for (int i = 0; i < 4; ++i)
#pragma unroll
        for (int j = 0; j < 4; ++j) acc[i][j] = fmaf(a[i], b[j], acc[i][j]);
    }
    __syncthreads();
  }
#pragma unroll
  for (int i = 0; i < 4; ++i) {
    float4 o = make_float4(acc[i][0], acc[i][1], acc[i][2], acc[i][3]);
    *(float4*)(Y + (size_t)(m0 + (ty << 2) + i) * 256 + n0 + (tx << 2)) = o;
  }
}

// ---- P[g] = Ahat[g] @ Y[g] + bias  (per graph 32x256) ---------------------
__global__ __launch_bounds__(256) void agg_k(const float* __restrict__ Yq,
                                             const float* __restrict__ Yc,
                                             const float* __restrict__ adj,
                                             const float* __restrict__ bias,
                                             float* __restrict__ Pq,
                                             float* __restrict__ Pc) {
  const int g = blockIdx.x, side = blockIdx.y;
  const float* Y = side ? Yc : Yq;
  float* P = side ? Pc : Pq;
  const float* A = adj + (size_t)(side * 256 + g) * 1024;
  __shared__ float As[1024];
  const int t = threadIdx.x;  // feature index 0..255
  for (int k = t; k < 1024; k += 256) As[k] = A[k];
  __syncthreads();
  float y[32];
#pragma unroll
  for (int j = 0; j < 32; ++j) y[j] = Y[(size_t)(g * 32 + j) * 256 + t];
  const float bf = bias[t];
#pragma unroll 4
  for (int i = 0; i < 32; ++i) {
    float acc = bf;
#pragma unroll
    for (int j = 0; j < 32; ++j) acc = fmaf(As[i * 32 + j], y[j], acc);
    P[(size_t)(g * 32 + i) * 256 + t] = acc;
  }
}

// ---- assemble 64x64 GED cost matrix for (b, l) ----------------------------
__global__ __launch_bounds__(256) void sim_k(const float* __restrict__ Pq,
                                             const float* __restrict__ Pc,
                                             const float* __restrict__ delp,
                                             const float* __restrict__ insp,
                                             float* __restrict__ sim, int l) {
  __shared__ float qs[32][256];
  __shared__ float cs[32][256];
  const int b = blockIdx.x, t = threadIdx.x;
  const float* qsrc = Pq + (size_t)b * 8192;
  const float* csrc = Pc + (size_t)b * 8192;
  float* dst = sim + ((size_t)b * 3 + l) * 4096;
  for (int k = t * 4; k < 8192; k += 1024) {
    *(float4*)((float*)qs + k) = *(const float4*)(qsrc + k);
    *(float4*)((float*)cs + k) = *(const float4*)(csrc + k);
  }
  __syncthreads();
  // main block: -q . c  (rotated f index keeps LDS banks conflict-free)
  const int ci = t & 31;
  const int qb = (t >> 5) << 2;
  float acc[4] = {0.f, 0.f, 0.f, 0.f};
#pragma unroll 8
  for (int f = 0; f < 256; ++f) {
    int idx = (f + ci) & 255;
    float cv = cs[ci][idx];
#pragma unroll
    for (int k = 0; k < 4; ++k) acc[k] = fmaf(qs[qb + k][idx], cv, acc[k]);
  }
#pragma unroll
  for (int k = 0; k < 4; ++k) dst[(qb + k) * 64 + ci] = -acc[k];
  // off-diagonal 99999 penalties + zero dummy block
  for (int k = t; k < 1024; k += 256) {
    int r = k >> 5, c = k & 31;
    if (r != c) {
      dst[r * 64 + 32 + c] = 99999.0f;
      dst[(32 + r) * 64 + c] = 99999.0f;
    }
    dst[(32 + r) * 64 + 32 + c] = 0.0f;
  }
  // delete / insert diagonals
  if (t < 64) {
    const int i = t & 31;
    const float* pvec = (t < 32) ? delp : insp;
    float a = 0.f;
#pragma unroll 8
    for (int f = 0; f < 256; ++f) {
      int idx = (f + i) & 255;
      float xv = (t < 32) ? qs[i][idx] : cs[i][idx];
      a = fmaf(xv, pvec[idx], a);
    }
    if (t < 32) dst[i * 64 + 32 + i] = -a;
    else        dst[(32 + i) * 64 + i] = -a;
  }
}

// ---- 64x64 Jonker-Volgenant shortest augmenting path, one wave per problem
__global__ __launch_bounds__(64) void lap_k(const float* __restrict__ sim,
                                            float* __restrict__ mcost) {
  __shared__ float cost[4096];
  __shared__ float u_lds[64];
  const int lane = threadIdx.x;
  const float* src = sim + (size_t)blockIdx.x * 4096;
  for (int k = lane; k < 4096; k += 64) cost[k] = src[k];
  u_lds[lane] = 0.0f;
  float v = 0.0f;       // lane owns column `lane`
  int col4row = -1;     // lane interpreted as row index
  int row4col = -1;     // lane interpreted as col index
  __syncthreads();

  for (int cur = 0; cur < 64; ++cur) {
    float shortest = LAP_INF;
    int path = -1;
    bool SC = false;
    int i = cur;
    float min_val = 0.0f;
    int sink = -1;
    while (true) {
      float r = min_val + cost[i * 64 + lane] - u_lds[i] - v;
      if (!SC && r < shortest) { shortest = r; path = i; }
      float m = SC ? LAP_INF : shortest;
      int idx = lane;
#pragma unroll
      for (int off = 32; off > 0; off >>= 1) {
        float om = __shfl_xor(m, off);
        int oi = __shfl_xor(idx, off);
        if (om < m || (om == m && oi < idx)) { m = om; idx = oi; }
      }
      min_val = m;
      int j = idx;
      if (lane == j) SC = true;
      int rj = __shfl(row4col, j);
      if (rj < 0) { sink = j; break; }
      i = rj;
    }
    // dual updates (scanned rows = row4col[j] for SC columns j != sink)
    float delta = min_val - shortest;
    __syncthreads();
    if (SC && lane != sink) u_lds[row4col] += delta;  // distinct rows per lane
    if (lane == 0) u_lds[cur] += min_val;
    if (SC) v -= delta;
    __syncthreads();
    // augment along alternating path
    int j = sink;
    while (true) {
      int i2 = __shfl(path, j);
      int jn = __shfl(col4row, i2);
      if (lane == j) row4col = i2;
      if (lane == i2) col4row = j;
      j = jn;
      if (i2 == cur) break;
    }
  }
  // total assignment cost = sum_i cost[i][col4row[i]]
  float c = cost[lane * 64 + col4row];
#pragma unroll
  for (int off = 32; off > 0; off >>= 1) c += __shfl_xor(c, off);
  if (lane == 0) mcost[blockIdx.x] = c;
}

// ---- head: sigmoid(sum_l mcost/S * w_l + b) -------------------------------
__global__ void final_k(const float* __restrict__ mcost,
                        const float* __restrict__ ot_w,
                        const float* __restrict__ ot_b,
                        float* __restrict__ out) {
  int b = threadIdx.x;
  if (b < 256) {
    float s = ot_b[0];
#pragma unroll
    for (int l = 0; l < 3; ++l)
      s += mcost[b * 3 + l] * (1.0f / 32.0f) * ot_w[l];
    out[b] = 1.0f / (1.0f + expf(-s));
  }
}

extern "C" void kernel_launch(void* const* d_in, const int* in_sizes, int n_in,
                              void* d_out, int out_size, void* d_ws, size_t ws_size,
                              hipStream_t stream) {
  const float* x_q  = (const float*)d_in[0];
  const float* x_c  = (const float*)d_in[1];
  const float* W0   = (const float*)d_in[2];
  const float* b0   = (const float*)d_in[3];
  const float* W1   = (const float*)d_in[4];
  const float* b1   = (const float*)d_in[5];
  const float* W2   = (const float*)d_in[6];
  const float* b2   = (const float*)d_in[7];
  const float* delp = (const float*)d_in[8];
  const float* insp = (const float*)d_in[9];
  const float* ot_w = (const float*)d_in[10];
  const float* ot_b = (const float*)d_in[11];
  const int* ei_q   = (const int*)d_in[12];
  const int* ei_c   = (const int*)d_in[13];
  float* out = (float*)d_out;

  float* ws    = (float*)d_ws;
  float* adj   = ws;                     // 512*1024            = 0.5M floats
  float* Yq    = adj + 512 * 1024;       // 8192*256            = 2M
  float* Yc    = Yq + 2097152;
  float* Pq    = Yc + 2097152;
  float* Pc    = Pq + 2097152;
  float* sim   = Pc + 2097152;           // 256*3*64*64         = 3M
  float* mcost = sim + 3145728;          // 768

  const int ne = in_sizes[12] / 2;       // directed edges per side (65536)

  hipMemsetAsync(adj, 0, 512 * 1024 * sizeof(float), stream);
  count_edges_k<<<dim3((ne + 255) / 256, 2), 256, 0, stream>>>(ei_q, ei_c, adj, ne);
  norm_adj_k<<<512, 256, 0, stream>>>(adj);

  const float* Ws[3] = {W0, W1, W2};
  const float* bs[3] = {b0, b1, b2};
  for (int l = 0; l < 3; ++l) {
    if (l == 0)
      gemm_k<false><<<dim3(128, 4, 2), 256, 0, stream>>>(x_q, x_c, Ws[0], Yq, Yc, 512);
    else
      gemm_k<true><<<dim3(128, 4, 2), 256, 0, stream>>>(Pq, Pc, Ws[l], Yq, Yc, 256);
    agg_k<<<dim3(256, 2), 256, 0, stream>>>(Yq, Yc, adj, bs[l], Pq, Pc);
    sim_k<<<256, 256, 0, stream>>>(Pq, Pc, delp + l * 256, insp + l * 256, sim, l);
  }
  lap_k<<<768, 64, 0, stream>>>(sim, mcost);
  final_k<<<1, 256, 0, stream>>>(mcost, ot_w, ot_b, out);
}

// Round 3
// 338.567 us; speedup vs baseline: 4.5426x; 4.5426x over previous
//
#include <hip/hip_runtime.h>
#include <math.h>

// ---------------------------------------------------------------------------
// GOTSim: GCN feats (dense per-graph adjacency) -> reduced 32x32 GED cost
// C[i][j] = min(-q_i.c_j, -q_i.del - c_j.ins)  (exactly equals the 64x64 LAP
// optimum with the 99999/dummy structure) -> batched 32x32 Jonker-Volgenant
// with DPP/readlane wave primitives -> sigmoid head.
// B=256 pairs, S=32 nodes, L=3 layers, FIN=512, F=256.
// ---------------------------------------------------------------------------

#define LAP_INF 1e30f

// ---- build adjacency counts (multi-edges counted, like segment_sum) -------
__global__ __launch_bounds__(256) void count_edges_k(const int* __restrict__ eiq,
                                                     const int* __restrict__ eic,
                                                     float* __restrict__ adj, int ne) {
  int e = blockIdx.x * 256 + threadIdx.x;
  if (e >= ne) return;
  const int side = blockIdx.y;
  const int* ei = side ? eic : eiq;
  int s = ei[e];
  int d = ei[ne + e];
  int g = d >> 5;  // S=32; edges never cross graphs by construction
  atomicAdd(&adj[((side << 8) + g) * 1024 + (d & 31) * 32 + (s & 31)], 1.0f);
}

// ---- add self loops, deg^-1/2 sym-normalize (in place) --------------------
__global__ __launch_bounds__(256) void norm_adj_k(float* __restrict__ adj) {
  __shared__ float s[1024];
  __shared__ float dinv[32];
  float* A = adj + (size_t)blockIdx.x * 1024;
  const int t = threadIdx.x;
  for (int k = t; k < 1024; k += 256) s[k] = A[k];
  __syncthreads();
  if (t < 32) s[t * 32 + t] += 1.0f;  // self loop
  __syncthreads();
  if (t < 32) {
    float d = 0.f;
#pragma unroll
    for (int j = 0; j < 32; ++j) d += s[t * 32 + j];
    dinv[t] = rsqrtf(d);  // deg = in-degree incl. self loop
  }
  __syncthreads();
  for (int k = t; k < 1024; k += 256)
    A[k] = s[k] * dinv[k >> 5] * dinv[k & 31];
}

// ---- Y = act(X) @ W  (M=8192, N=256), 64x64 tile, 4x4 per thread ----------
template <bool RELU>
__global__ __launch_bounds__(256) void gemm_k(const float* __restrict__ Xq,
                                              const float* __restrict__ Xc,
                                              const float* __restrict__ W,
                                              float* __restrict__ Yq,
                                              float* __restrict__ Yc, int K) {
  const float* X = blockIdx.z ? Xc : Xq;
  float* Y = blockIdx.z ? Yc : Yq;
  const int m0 = blockIdx.x * 64, n0 = blockIdx.y * 64;
  __shared__ float As[16][64];
  __shared__ float Bs[16][64];
  const int t = threadIdx.x;
  const int tx = t & 15, ty = t >> 4;
  const int lam = t >> 2, lak = (t & 3) << 2;  // A-tile load: row, k-quad
  const int lbk = t >> 4, lbn = (t & 15) << 2; // B-tile load
  float acc[4][4] = {};
  for (int k0 = 0; k0 < K; k0 += 16) {
    float4 av = *(const float4*)(X + (size_t)(m0 + lam) * K + k0 + lak);
    float4 bv = *(const float4*)(W + (size_t)(k0 + lbk) * 256 + n0 + lbn);
    if (RELU) {
      av.x = fmaxf(av.x, 0.f); av.y = fmaxf(av.y, 0.f);
      av.z = fmaxf(av.z, 0.f); av.w = fmaxf(av.w, 0.f);
    }
    As[lak + 0][lam] = av.x;
    As[lak + 1][lam] = av.y;
    As[lak + 2][lam] = av.z;
    As[lak + 3][lam] = av.w;
    *(float4*)&Bs[lbk][lbn] = bv;
    __syncthreads();
#pragma unroll
    for (int kk = 0; kk < 16; ++kk) {
      float a[4], b[4];
      *(float4*)a = *(const float4*)&As[kk][ty << 2];
      *(float4*)b = *(const float4*)&Bs[kk][tx << 2];
#pragma unroll
      for (int i = 0; i < 4; ++i)
#pragma unroll
        for (int j = 0; j < 4; ++j) acc[i][j] = fmaf(a[i], b[j], acc[i][j]);
    }
    __syncthreads();
  }
#pragma unroll
  for (int i = 0; i < 4; ++i) {
    float4 o = make_float4(acc[i][0], acc[i][1], acc[i][2], acc[i][3]);
    *(float4*)(Y + (size_t)(m0 + (ty << 2) + i) * 256 + n0 + (tx << 2)) = o;
  }
}

// ---- P[g] = Ahat[g] @ Y[g] + bias  (per graph 32x256) ---------------------
__global__ __launch_bounds__(256) void agg_k(const float* __restrict__ Yq,
                                             const float* __restrict__ Yc,
                                             const float* __restrict__ adj,
                                             const float* __restrict__ bias,
                                             float* __restrict__ Pq,
                                             float* __restrict__ Pc) {
  const int g = blockIdx.x, side = blockIdx.y;
  const float* Y = side ? Yc : Yq;
  float* P = side ? Pc : Pq;
  const float* A = adj + (size_t)(side * 256 + g) * 1024;
  __shared__ float As[1024];
  const int t = threadIdx.x;  // feature index 0..255
  for (int k = t; k < 1024; k += 256) As[k] = A[k];
  __syncthreads();
  float y[32];
#pragma unroll
  for (int j = 0; j < 32; ++j) y[j] = Y[(size_t)(g * 32 + j) * 256 + t];
  const float bf = bias[t];
#pragma unroll 4
  for (int i = 0; i < 32; ++i) {
    float acc = bf;
#pragma unroll
    for (int j = 0; j < 32; ++j) acc = fmaf(As[i * 32 + j], y[j], acc);
    P[(size_t)(g * 32 + i) * 256 + t] = acc;
  }
}

// ---- assemble reduced 32x32 GED cost matrix for (b, l) --------------------
__global__ __launch_bounds__(256) void sim_k(const float* __restrict__ Pq,
                                             const float* __restrict__ Pc,
                                             const float* __restrict__ delp,
                                             const float* __restrict__ insp,
                                             float* __restrict__ sim, int l) {
  __shared__ float qs[32][256];
  __shared__ float cs[32][256];
  __shared__ float dq[32];   // -q_i . del
  __shared__ float dic[32];  // -c_j . ins
  const int b = blockIdx.x, t = threadIdx.x;
  const float* qsrc = Pq + (size_t)b * 8192;
  const float* csrc = Pc + (size_t)b * 8192;
  float* dst = sim + ((size_t)b * 3 + l) * 1024;
  for (int k = t * 4; k < 8192; k += 1024) {
    *(float4*)((float*)qs + k) = *(const float4*)(qsrc + k);
    *(float4*)((float*)cs + k) = *(const float4*)(csrc + k);
  }
  __syncthreads();
  if (t < 64) {
    const int i = t & 31;
    const float* pvec = (t < 32) ? delp : insp;
    float a = 0.f;
#pragma unroll 8
    for (int f = 0; f < 256; ++f) {
      int idx = (f + i) & 255;
      float xv = (t < 32) ? qs[i][idx] : cs[i][idx];
      a = fmaf(xv, pvec[idx], a);
    }
    if (t < 32) dq[i] = -a;
    else        dic[i] = -a;
  }
  __syncthreads();
  // main block: -q . c  (rotated f index keeps LDS banks conflict-free)
  const int ci = t & 31;
  const int qb = (t >> 5) << 2;
  float acc[4] = {0.f, 0.f, 0.f, 0.f};
#pragma unroll 8
  for (int f = 0; f < 256; ++f) {
    int idx = (f + ci) & 255;
    float cv = cs[ci][idx];
#pragma unroll
    for (int k = 0; k < 4; ++k) acc[k] = fmaf(qs[qb + k][idx], cv, acc[k]);
  }
  const float dj = dic[ci];
#pragma unroll
  for (int k = 0; k < 4; ++k) {
    float alt = dq[qb + k] + dj;  // delete row + insert col
    dst[(qb + k) * 32 + ci] = fminf(-acc[k], alt);
  }
}

// ---- 32x32 Jonker-Volgenant, one problem per wave, lanes 0-31 -------------
// DPP row_ror min-reduce (VALU) + readlane/ballot argmin: no LDS-pipe ops on
// the reduction chain. DPP ctrl must be an immediate -> template parameter.
template <int CTRL>
__device__ __forceinline__ float dpp_ror_min(float x) {
  int y = __builtin_amdgcn_update_dpp(0, __float_as_int(x), CTRL, 0xf, 0xf, true);
  return fminf(x, __int_as_float(y));
}
template <int CTRL>
__device__ __forceinline__ float dpp_ror_add(float x) {
  int y = __builtin_amdgcn_update_dpp(0, __float_as_int(x), CTRL, 0xf, 0xf, true);
  return x + __int_as_float(y);
}
__device__ __forceinline__ float rdlane_f(float x, int l) {
  return __int_as_float(__builtin_amdgcn_readlane(__float_as_int(x), l));
}

__global__ __launch_bounds__(64) void lap_k(const float* __restrict__ sim,
                                            float* __restrict__ mcost) {
  __shared__ float C[1024];
  __shared__ float u[32];
  const int lane = threadIdx.x;
  const float* src = sim + (size_t)blockIdx.x * 1024;
  for (int k = lane; k < 1024; k += 64) C[k] = src[k];
  if (lane >= 32) return;
  u[lane] = 0.0f;
  float v = 0.0f;     // lane owns column `lane`
  int col4row = -1;   // lane as row index
  int row4col = -1;   // lane as col index

  for (int cur = 0; cur < 32; ++cur) {
    float shortest = LAP_INF;
    int path = -1;
    bool SC = false;
    int i = cur;
    float minval = 0.0f;
    int sink;
    while (true) {
      float r = minval + C[i * 32 + lane] - u[i] - v;
      bool better = (!SC) && (r < shortest);
      shortest = better ? r : shortest;
      path = better ? i : path;
      float masked = SC ? LAP_INF : shortest;
      // 32-lane min: 4 DPP rors within 16-rows, then bridge rows via readlane
      float m = masked;
      m = dpp_ror_min<0x121>(m);  // row_ror:1
      m = dpp_ror_min<0x122>(m);  // row_ror:2
      m = dpp_ror_min<0x124>(m);  // row_ror:4
      m = dpp_ror_min<0x128>(m);  // row_ror:8
      float mv = fminf(rdlane_f(m, 15), rdlane_f(m, 31));
      unsigned long long bal = __ballot(masked == mv);  // exact: min keeps bits
      int j = __ffsll((unsigned long long)bal) - 1;     // lowest index tie-break
      minval = mv;
      SC = SC || (lane == j);
      int rj = __builtin_amdgcn_readlane(row4col, j);
      if (rj < 0) { sink = j; break; }
      i = rj;
    }
    // dual updates: u over scanned rows, v over SC columns
    float delta = minval - shortest;
    if (SC && lane != sink) u[row4col] += delta;  // distinct rows per lane
    if (lane == cur) u[cur] += minval;            // row cur unassigned: no clash
    if (SC) v -= delta;
    // augment alternating path (all lookups uniform readlanes)
    int j = sink;
    while (true) {
      int i2 = __builtin_amdgcn_readlane(path, j);
      int jn = __builtin_amdgcn_readlane(col4row, i2);
      if (lane == j) row4col = i2;
      if (lane == i2) col4row = j;
      j = jn;
      if (i2 == cur) break;
    }
  }
  // total assignment cost = sum_i C[i][col4row[i]]
  float c = C[lane * 32 + col4row];
  c = dpp_ror_add<0x121>(c);
  c = dpp_ror_add<0x122>(c);
  c = dpp_ror_add<0x124>(c);
  c = dpp_ror_add<0x128>(c);
  float tot = rdlane_f(c, 0) + rdlane_f(c, 16);
  if (lane == 0) mcost[blockIdx.x] = tot;
}

// ---- head: sigmoid(sum_l mcost/S * w_l + b) -------------------------------
__global__ void final_k(const float* __restrict__ mcost,
                        const float* __restrict__ ot_w,
                        const float* __restrict__ ot_b,
                        float* __restrict__ out) {
  int b = threadIdx.x;
  if (b < 256) {
    float s = ot_b[0];
#pragma unroll
    for (int l = 0; l < 3; ++l)
      s += mcost[b * 3 + l] * (1.0f / 32.0f) * ot_w[l];
    out[b] = 1.0f / (1.0f + expf(-s));
  }
}

extern "C" void kernel_launch(void* const* d_in, const int* in_sizes, int n_in,
                              void* d_out, int out_size, void* d_ws, size_t ws_size,
                              hipStream_t stream) {
  const float* x_q  = (const float*)d_in[0];
  const float* x_c  = (const float*)d_in[1];
  const float* W0   = (const float*)d_in[2];
  const float* b0   = (const float*)d_in[3];
  const float* W1   = (const float*)d_in[4];
  const float* b1   = (const float*)d_in[5];
  const float* W2   = (const float*)d_in[6];
  const float* b2   = (const float*)d_in[7];
  const float* delp = (const float*)d_in[8];
  const float* insp = (const float*)d_in[9];
  const float* ot_w = (const float*)d_in[10];
  const float* ot_b = (const float*)d_in[11];
  const int* ei_q   = (const int*)d_in[12];
  const int* ei_c   = (const int*)d_in[13];
  float* out = (float*)d_out;

  float* ws    = (float*)d_ws;
  float* adj   = ws;                     // 512*1024
  float* Yq    = adj + 512 * 1024;       // 8192*256
  float* Yc    = Yq + 2097152;
  float* Pq    = Yc + 2097152;
  float* Pc    = Pq + 2097152;
  float* sim   = Pc + 2097152;           // 768*1024 (reduced 32x32 C)
  float* mcost = sim + 786432;           // 768

  const int ne = in_sizes[12] / 2;       // directed edges per side (65536)

  (void)hipMemsetAsync(adj, 0, 512 * 1024 * sizeof(float), stream);
  count_edges_k<<<dim3((ne + 255) / 256, 2), 256, 0, stream>>>(ei_q, ei_c, adj, ne);
  norm_adj_k<<<512, 256, 0, stream>>>(adj);

  const float* Ws[3] = {W0, W1, W2};
  const float* bs[3] = {b0, b1, b2};
  for (int l = 0; l < 3; ++l) {
    if (l == 0)
      gemm_k<false><<<dim3(128, 4, 2), 256, 0, stream>>>(x_q, x_c, Ws[0], Yq, Yc, 512);
    else
      gemm_k<true><<<dim3(128, 4, 2), 256, 0, stream>>>(Pq, Pc, Ws[l], Yq, Yc, 256);
    agg_k<<<dim3(256, 2), 256, 0, stream>>>(Yq, Yc, adj, bs[l], Pq, Pc);
    sim_k<<<256, 256, 0, stream>>>(Pq, Pc, delp + l * 256, insp + l * 256, sim, l);
  }
  lap_k<<<768, 64, 0, stream>>>(sim, mcost);
  final_k<<<1, 256, 0, stream>>>(mcost, ot_w, ot_b, out);
}

// Round 4
// 275.195 us; speedup vs baseline: 5.5887x; 1.2303x over previous
//
#include <hip/hip_runtime.h>
#include <math.h>

// ---------------------------------------------------------------------------
// GOTSim: GCN feats (bf16 hi/lo-split MFMA GEMM + dense per-graph adjacency)
// -> reduced 32x32 GED cost -> batched JV LAP (column-reduction init,
// register duals, DPP/readlane reductions) -> sigmoid head.
// B=256 pairs, S=32 nodes, L=3 layers, FIN=512, F=256.
// ---------------------------------------------------------------------------

#define LAP_INF 1e30f

typedef __attribute__((ext_vector_type(8))) short short8;
typedef __attribute__((ext_vector_type(4))) float f32x4;

// ---- build adjacency counts (multi-edges counted, like segment_sum) -------
__global__ __launch_bounds__(256) void count_edges_k(const int* __restrict__ eiq,
                                                     const int* __restrict__ eic,
                                                     float* __restrict__ adj, int ne) {
  int e = blockIdx.x * 256 + threadIdx.x;
  if (e >= ne) return;
  const int side = blockIdx.y;
  const int* ei = side ? eic : eiq;
  int s = ei[e];
  int d = ei[ne + e];
  int g = d >> 5;
  atomicAdd(&adj[((side << 8) + g) * 1024 + (d & 31) * 32 + (s & 31)], 1.0f);
}

// ---- add self loops, deg^-1/2 sym-normalize (in place) --------------------
__global__ __launch_bounds__(256) void norm_adj_k(float* __restrict__ adj) {
  __shared__ float s[1024];
  __shared__ float dinv[32];
  float* A = adj + (size_t)blockIdx.x * 1024;
  const int t = threadIdx.x;
  for (int k = t; k < 1024; k += 256) s[k] = A[k];
  __syncthreads();
  if (t < 32) s[t * 32 + t] += 1.0f;
  __syncthreads();
  if (t < 32) {
    float d = 0.f;
#pragma unroll
    for (int j = 0; j < 32; ++j) d += s[t * 32 + j];
    dinv[t] = rsqrtf(d);
  }
  __syncthreads();
  for (int k = t; k < 1024; k += 256)
    A[k] = s[k] * dinv[k >> 5] * dinv[k & 31];
}

// ---- W [K][256] -> Wt [256][K] fp32 transpose -----------------------------
__global__ __launch_bounds__(256) void wt_k(const float* __restrict__ W,
                                            float* __restrict__ Wt, int K) {
  __shared__ float tile[32][33];
  const int k0 = blockIdx.x * 32, n0 = blockIdx.y * 32;
  const int tr = threadIdx.x & 31, tc = threadIdx.x >> 5;
  for (int rr = tc; rr < 32; rr += 8)
    tile[rr][tr] = W[(size_t)(k0 + rr) * 256 + n0 + tr];
  __syncthreads();
  for (int rr = tc; rr < 32; rr += 8)
    Wt[(size_t)(n0 + rr) * K + k0 + tr] = tile[tr][rr];
}

// ---- bf16 split helpers ---------------------------------------------------
__device__ __forceinline__ unsigned short bf16_rne(float x) {
  unsigned u = __float_as_uint(x);
  return (unsigned short)((u + 0x7fffu + ((u >> 16) & 1u)) >> 16);
}

// ---- Y = act(X) @ W via hi/lo bf16-split MFMA -----------------------------
// 128x128 tile, 4 waves, K-step 32. A fp32 [M][K]; Wt fp32 [256][K].
// LDS row stride 40 shorts (80 B): 16B-aligned b128 frags, 2-way banks only.
template <bool RELU, int K>
__global__ __launch_bounds__(256) void gemm_mfma_k(const float* __restrict__ Aq,
                                                   const float* __restrict__ Ac,
                                                   const float* __restrict__ Wt,
                                                   float* __restrict__ Y) {
  const float* A = blockIdx.z ? Ac : Aq;
  float* Yp = Y + (size_t)blockIdx.z * 2097152;
  const int m0 = blockIdx.x * 128;
  const int n0 = blockIdx.y * 128;
  __shared__ __align__(16) unsigned short As[2][128 * 40];  // [plane][row*40+k]
  __shared__ __align__(16) unsigned short Bs[2][128 * 40];
  const int t = threadIdx.x;
  const int wave = t >> 6, lane = t & 63;
  const int lrow = lane & 15, kgrp = lane >> 4;

  f32x4 acc[2][8];
#pragma unroll
  for (int i = 0; i < 2; ++i)
#pragma unroll
    for (int j = 0; j < 8; ++j) acc[i][j] = (f32x4){0.f, 0.f, 0.f, 0.f};

  for (int kt = 0; kt < K; kt += 32) {
    // stage: fp32 global -> hi/lo bf16 LDS (128 rows x 32 k each for A and B)
#pragma unroll
    for (int p = 0; p < 4; ++p) {
      const int u = t + p * 256;
      const int row = u >> 3, seg = u & 7;
      float4 xv = *(const float4*)(A + (size_t)(m0 + row) * K + kt + seg * 4);
      if (RELU) {
        xv.x = fmaxf(xv.x, 0.f); xv.y = fmaxf(xv.y, 0.f);
        xv.z = fmaxf(xv.z, 0.f); xv.w = fmaxf(xv.w, 0.f);
      }
      ushort4 h, l;
      h.x = bf16_rne(xv.x); h.y = bf16_rne(xv.y);
      h.z = bf16_rne(xv.z); h.w = bf16_rne(xv.w);
      l.x = (unsigned short)(__float_as_uint(xv.x - __uint_as_float((unsigned)h.x << 16)) >> 16);
      l.y = (unsigned short)(__float_as_uint(xv.y - __uint_as_float((unsigned)h.y << 16)) >> 16);
      l.z = (unsigned short)(__float_as_uint(xv.z - __uint_as_float((unsigned)h.z << 16)) >> 16);
      l.w = (unsigned short)(__float_as_uint(xv.w - __uint_as_float((unsigned)h.w << 16)) >> 16);
      *(ushort4*)&As[0][row * 40 + seg * 4] = h;
      *(ushort4*)&As[1][row * 40 + seg * 4] = l;
      float4 wv = *(const float4*)(Wt + (size_t)(n0 + row) * K + kt + seg * 4);
      ushort4 wh, wl;
      wh.x = bf16_rne(wv.x); wh.y = bf16_rne(wv.y);
      wh.z = bf16_rne(wv.z); wh.w = bf16_rne(wv.w);
      wl.x = (unsigned short)(__float_as_uint(wv.x - __uint_as_float((unsigned)wh.x << 16)) >> 16);
      wl.y = (unsigned short)(__float_as_uint(wv.y - __uint_as_float((unsigned)wh.y << 16)) >> 16);
      wl.z = (unsigned short)(__float_as_uint(wv.z - __uint_as_float((unsigned)wh.z << 16)) >> 16);
      wl.w = (unsigned short)(__float_as_uint(wv.w - __uint_as_float((unsigned)wh.w << 16)) >> 16);
      *(ushort4*)&Bs[0][row * 40 + seg * 4] = wh;
      *(ushort4*)&Bs[1][row * 40 + seg * 4] = wl;
    }
    __syncthreads();
    short8 ah[2], al[2];
#pragma unroll
    for (int mf = 0; mf < 2; ++mf) {
      const int off = (wave * 32 + mf * 16 + lrow) * 40 + kgrp * 8;
      ah[mf] = *(const short8*)&As[0][off];
      al[mf] = *(const short8*)&As[1][off];
    }
#pragma unroll
    for (int nf = 0; nf < 8; ++nf) {
      const int off = (nf * 16 + lrow) * 40 + kgrp * 8;
      short8 bh = *(const short8*)&Bs[0][off];
      short8 bl = *(const short8*)&Bs[1][off];
#pragma unroll
      for (int mf = 0; mf < 2; ++mf) {
        acc[mf][nf] = __builtin_amdgcn_mfma_f32_16x16x32_bf16(ah[mf], bh, acc[mf][nf], 0, 0, 0);
        acc[mf][nf] = __builtin_amdgcn_mfma_f32_16x16x32_bf16(ah[mf], bl, acc[mf][nf], 0, 0, 0);
        acc[mf][nf] = __builtin_amdgcn_mfma_f32_16x16x32_bf16(al[mf], bh, acc[mf][nf], 0, 0, 0);
      }
    }
    __syncthreads();
  }
  // epilogue: D row=(lane>>4)*4+r, col=lane&15
#pragma unroll
  for (int mf = 0; mf < 2; ++mf)
#pragma unroll
    for (int nf = 0; nf < 8; ++nf)
#pragma unroll
      for (int r = 0; r < 4; ++r)
        Yp[(size_t)(m0 + wave * 32 + mf * 16 + kgrp * 4 + r) * 256 + n0 + nf * 16 + lrow] =
            acc[mf][nf][r];
}

// ---- P[g] = Ahat[g] @ Y[g] + bias  (per graph 32x256) ---------------------
__global__ __launch_bounds__(256) void agg_k(const float* __restrict__ Yq,
                                             const float* __restrict__ Yc,
                                             const float* __restrict__ adj,
                                             const float* __restrict__ bias,
                                             float* __restrict__ Pq,
                                             float* __restrict__ Pc) {
  const int g = blockIdx.x, side = blockIdx.y;
  const float* Y = side ? Yc : Yq;
  float* P = side ? Pc : Pq;
  const float* A = adj + (size_t)(side * 256 + g) * 1024;
  __shared__ float As[1024];
  const int t = threadIdx.x;
  for (int k = t; k < 1024; k += 256) As[k] = A[k];
  __syncthreads();
  float y[32];
#pragma unroll
  for (int j = 0; j < 32; ++j) y[j] = Y[(size_t)(g * 32 + j) * 256 + t];
  const float bf = bias[t];
#pragma unroll 4
  for (int i = 0; i < 32; ++i) {
    float acc = bf;
#pragma unroll
    for (int j = 0; j < 32; ++j) acc = fmaf(As[i * 32 + j], y[j], acc);
    P[(size_t)(g * 32 + i) * 256 + t] = acc;
  }
}

// ---- assemble reduced 32x32 GED cost matrix for (b, l) --------------------
__global__ __launch_bounds__(256) void sim_k(const float* __restrict__ Pq,
                                             const float* __restrict__ Pc,
                                             const float* __restrict__ delp,
                                             const float* __restrict__ insp,
                                             float* __restrict__ sim, int l) {
  __shared__ float qs[32][256];
  __shared__ float cs[32][256];
  __shared__ float dq[32];
  __shared__ float dic[32];
  const int b = blockIdx.x, t = threadIdx.x;
  const float* qsrc = Pq + (size_t)b * 8192;
  const float* csrc = Pc + (size_t)b * 8192;
  float* dst = sim + ((size_t)b * 3 + l) * 1024;
  for (int k = t * 4; k < 8192; k += 1024) {
    *(float4*)((float*)qs + k) = *(const float4*)(qsrc + k);
    *(float4*)((float*)cs + k) = *(const float4*)(csrc + k);
  }
  __syncthreads();
  if (t < 64) {
    const int i = t & 31;
    const float* pvec = (t < 32) ? delp : insp;
    float a = 0.f;
#pragma unroll 8
    for (int f = 0; f < 256; ++f) {
      int idx = (f + i) & 255;
      float xv = (t < 32) ? qs[i][idx] : cs[i][idx];
      a = fmaf(xv, pvec[idx], a);
    }
    if (t < 32) dq[i] = -a;
    else        dic[i] = -a;
  }
  __syncthreads();
  const int ci = t & 31;
  const int qb = (t >> 5) << 2;
  float acc[4] = {0.f, 0.f, 0.f, 0.f};
#pragma unroll 8
  for (int f = 0; f < 256; ++f) {
    int idx = (f + ci) & 255;
    float cv = cs[ci][idx];
#pragma unroll
    for (int k = 0; k < 4; ++k) acc[k] = fmaf(qs[qb + k][idx], cv, acc[k]);
  }
  const float dj = dic[ci];
#pragma unroll
  for (int k = 0; k < 4; ++k) {
    float alt = dq[qb + k] + dj;
    dst[(qb + k) * 32 + ci] = fminf(-acc[k], alt);
  }
}

// ---- 32x32 Jonker-Volgenant with column-reduction init --------------------
template <int CTRL>
__device__ __forceinline__ float dpp_ror_min(float x) {
  int y = __builtin_amdgcn_update_dpp(0, __float_as_int(x), CTRL, 0xf, 0xf, true);
  return fminf(x, __int_as_float(y));
}
template <int CTRL>
__device__ __forceinline__ float dpp_ror_add(float x) {
  int y = __builtin_amdgcn_update_dpp(0, __float_as_int(x), CTRL, 0xf, 0xf, true);
  return x + __int_as_float(y);
}
__device__ __forceinline__ float rdlane_f(float x, int l) {
  return __int_as_float(__builtin_amdgcn_readlane(__float_as_int(x), l));
}

__global__ __launch_bounds__(64) void lap_k(const float* __restrict__ sim,
                                            float* __restrict__ mcost) {
  __shared__ float C[1024];
  const int lane = threadIdx.x;
  const float* src = sim + (size_t)blockIdx.x * 1024;
  for (int k = lane; k < 1024; k += 64) C[k] = src[k];
  if (lane >= 32) return;  // same-wave LDS ordering covers the staging writes

  // ---- column reduction: v_j = min_i C[i][j]; greedy tight matching -------
  float minv = LAP_INF;
  int imin = 0;
#pragma unroll
  for (int i = 0; i < 32; ++i) {
    float val = C[i * 32 + lane];
    if (val < minv) { minv = val; imin = i; }
  }
  float vj = minv;     // lane as column: dual v
  float u = 0.0f;      // lane as row: dual u
  int col4row = -1;    // lane as row
  int row4col = -1;    // lane as col
#pragma unroll
  for (int r = 0; r < 32; ++r) {
    unsigned long long bal = __ballot(imin == r);
    if (bal) {
      int j = 63 - __clzll(bal);  // one claiming column per row
      if (lane == j) row4col = r;
      if (lane == r) col4row = j;
    }
  }
  unsigned long long freemask = __ballot(col4row < 0);

  // ---- shortest augmenting path for remaining free rows -------------------
  while (freemask) {
    const int cur = __ffsll(freemask) - 1;
    freemask &= freemask - 1;
    float shortest = LAP_INF;
    int path = -1;
    bool SC = false;
    int i = cur;
    float minval = 0.0f;
    int sink;
    while (true) {
      float ui = rdlane_f(u, i);
      float r = minval + C[i * 32 + lane] - ui - vj;
      bool better = (!SC) && (r < shortest);
      shortest = better ? r : shortest;
      path = better ? i : path;
      float masked = SC ? LAP_INF : shortest;
      float m = masked;
      m = dpp_ror_min<0x121>(m);
      m = dpp_ror_min<0x122>(m);
      m = dpp_ror_min<0x124>(m);
      m = dpp_ror_min<0x128>(m);
      float mv = fminf(rdlane_f(m, 0), rdlane_f(m, 16));
      unsigned long long bal = __ballot(masked == mv);  // exact: min keeps bits
      int j = __ffsll(bal) - 1;                         // lowest-index tie-break
      minval = mv;
      SC = SC || (lane == j);
      int rj = __builtin_amdgcn_readlane(row4col, j);
      if (rj < 0) { sink = j; break; }
      i = rj;
    }
    // dual updates (v: lane as column; u: lane as row, via SC mask)
    unsigned long long scmask = __ballot(SC);
    if (SC) vj -= minval - shortest;
    int sidx = (col4row < 0) ? lane : col4row;
    float sh_j0 = __shfl(shortest, sidx);
    bool scanned = (col4row >= 0) && ((scmask >> col4row) & 1ull) && (col4row != sink);
    if (lane == cur) u += minval;
    else if (scanned) u += minval - sh_j0;
    // augment alternating path
    int j = sink;
    while (true) {
      int i2 = __builtin_amdgcn_readlane(path, j);
      int jn = __builtin_amdgcn_readlane(col4row, i2);
      if (lane == j) row4col = i2;
      if (lane == i2) col4row = j;
      j = jn;
      if (i2 == cur) break;
    }
  }
  // total assignment cost
  float c = C[lane * 32 + col4row];
  c = dpp_ror_add<0x121>(c);
  c = dpp_ror_add<0x122>(c);
  c = dpp_ror_add<0x124>(c);
  c = dpp_ror_add<0x128>(c);
  float tot = rdlane_f(c, 0) + rdlane_f(c, 16);
  if (lane == 0) mcost[blockIdx.x] = tot;
}

// ---- head: sigmoid(sum_l mcost/S * w_l + b) -------------------------------
__global__ void final_k(const float* __restrict__ mcost,
                        const float* __restrict__ ot_w,
                        const float* __restrict__ ot_b,
                        float* __restrict__ out) {
  int b = threadIdx.x;
  if (b < 256) {
    float s = ot_b[0];
#pragma unroll
    for (int l = 0; l < 3; ++l)
      s += mcost[b * 3 + l] * (1.0f / 32.0f) * ot_w[l];
    out[b] = 1.0f / (1.0f + expf(-s));
  }
}

extern "C" void kernel_launch(void* const* d_in, const int* in_sizes, int n_in,
                              void* d_out, int out_size, void* d_ws, size_t ws_size,
                              hipStream_t stream) {
  const float* x_q  = (const float*)d_in[0];
  const float* x_c  = (const float*)d_in[1];
  const float* W0   = (const float*)d_in[2];
  const float* b0   = (const float*)d_in[3];
  const float* W1   = (const float*)d_in[4];
  const float* b1   = (const float*)d_in[5];
  const float* W2   = (const float*)d_in[6];
  const float* b2   = (const float*)d_in[7];
  const float* delp = (const float*)d_in[8];
  const float* insp = (const float*)d_in[9];
  const float* ot_w = (const float*)d_in[10];
  const float* ot_b = (const float*)d_in[11];
  const int* ei_q   = (const int*)d_in[12];
  const int* ei_c   = (const int*)d_in[13];
  float* out = (float*)d_out;

  float* ws    = (float*)d_ws;
  float* adj   = ws;                 // 512*1024              = 524288
  float* Y     = adj + 524288;       // 2*8192*256            = 4194304
  float* Pq    = Y + 4194304;        // 8192*256              = 2097152
  float* Pc    = Pq + 2097152;       // 8192*256              = 2097152
  float* sim   = Pc + 2097152;       // 768*1024              = 786432
  float* mcost = sim + 786432;       // 768
  float* Wt    = mcost + 768;        // 256*512               = 131072

  const int ne = in_sizes[12] / 2;

  (void)hipMemsetAsync(adj, 0, 512 * 1024 * sizeof(float), stream);
  count_edges_k<<<dim3((ne + 255) / 256, 2), 256, 0, stream>>>(ei_q, ei_c, adj, ne);
  norm_adj_k<<<512, 256, 0, stream>>>(adj);

  const float* bs[3] = {b0, b1, b2};

  // layer 0 (K=512, no relu)
  wt_k<<<dim3(16, 8), 256, 0, stream>>>(W0, Wt, 512);
  gemm_mfma_k<false, 512><<<dim3(64, 2, 2), 256, 0, stream>>>(x_q, x_c, Wt, Y);
  agg_k<<<dim3(256, 2), 256, 0, stream>>>(Y, Y + 2097152, adj, bs[0], Pq, Pc);
  sim_k<<<256, 256, 0, stream>>>(Pq, Pc, delp, insp, sim, 0);
  // layers 1-2 (K=256, relu on input)
  wt_k<<<dim3(8, 8), 256, 0, stream>>>(W1, Wt, 256);
  gemm_mfma_k<true, 256><<<dim3(64, 2, 2), 256, 0, stream>>>(Pq, Pc, Wt, Y);
  agg_k<<<dim3(256, 2), 256, 0, stream>>>(Y, Y + 2097152, adj, bs[1], Pq, Pc);
  sim_k<<<256, 256, 0, stream>>>(Pq, Pc, delp + 256, insp + 256, sim, 1);

  wt_k<<<dim3(8, 8), 256, 0, stream>>>(W2, Wt, 256);
  gemm_mfma_k<true, 256><<<dim3(64, 2, 2), 256, 0, stream>>>(Pq, Pc, Wt, Y);
  agg_k<<<dim3(256, 2), 256, 0, stream>>>(Y, Y + 2097152, adj, bs[2], Pq, Pc);
  sim_k<<<256, 256, 0, stream>>>(Pq, Pc, delp + 512, insp + 512, sim, 2);

  lap_k<<<768, 64, 0, stream>>>(sim, mcost);
  final_k<<<1, 256, 0, stream>>>(mcost, ot_w, ot_b, out);
}